// Round 2
// baseline (422.806 us; speedup 1.0000x reference)
//
#include <hip/hip_runtime.h>

// VQ: x (32,64,64,64) fp32 NCHW, embed (512,64) fp32.
// N = 131072 rows of D=64; K=512 codes.
// out = [quantized: N*64 floats (NHWC)] ++ [indices: N floats]
//
// R2: hold the x-row in 16 NAMED float4 regs (R1's xr[64] array was demoted
// to scratch: VGPR_Count=36, WRITE_SIZE=146MB spill traffic, VALUBusy=34%).
// 512-FMA k-block body macro-expanded, interleaved across 8 acc chains.

#define VQ_N 131072
#define VQ_D 64
#define VQ_K 512
#define VQ_HW 4096   // H*W = 64*64

__global__ __launch_bounds__(256) void vq_esq_kernel(
    const float* __restrict__ embed, float* __restrict__ esq) {
    int k = blockIdx.x * blockDim.x + threadIdx.x;
    if (k >= VQ_K) return;
    const float* e = embed + k * VQ_D;
    float p0 = 0.f, p1 = 0.f, p2 = 0.f, p3 = 0.f;
#pragma unroll
    for (int d = 0; d < VQ_D; d += 4) {
        p0 = fmaf(e[d + 0], e[d + 0], p0);
        p1 = fmaf(e[d + 1], e[d + 1], p1);
        p2 = fmaf(e[d + 2], e[d + 2], p2);
        p3 = fmaf(e[d + 3], e[d + 3], p3);
    }
    esq[k] = (p0 + p1) + (p2 + p3);
}

// one FMA into each of the 8 chains for x-scalar xv at depth d
#define ROW8(xv, d)                                  \
    acc0 = fmaf(xv, e0[0 * VQ_D + (d)], acc0);       \
    acc1 = fmaf(xv, e0[1 * VQ_D + (d)], acc1);       \
    acc2 = fmaf(xv, e0[2 * VQ_D + (d)], acc2);       \
    acc3 = fmaf(xv, e0[3 * VQ_D + (d)], acc3);       \
    acc4 = fmaf(xv, e0[4 * VQ_D + (d)], acc4);       \
    acc5 = fmaf(xv, e0[5 * VQ_D + (d)], acc5);       \
    acc6 = fmaf(xv, e0[6 * VQ_D + (d)], acc6);       \
    acc7 = fmaf(xv, e0[7 * VQ_D + (d)], acc7);

#define BLK4(Xv, dbase)                              \
    ROW8((Xv).x, (dbase) + 0)                        \
    ROW8((Xv).y, (dbase) + 1)                        \
    ROW8((Xv).z, (dbase) + 2)                        \
    ROW8((Xv).w, (dbase) + 3)

#define LD4(Xv, c)                                   \
    (Xv).x = xp[((c) + 0) * VQ_HW];                  \
    (Xv).y = xp[((c) + 1) * VQ_HW];                  \
    (Xv).z = xp[((c) + 2) * VQ_HW];                  \
    (Xv).w = xp[((c) + 3) * VQ_HW];

__global__ __launch_bounds__(256) void vq_main_kernel(
    const float* __restrict__ x,
    const float* __restrict__ embed,
    const float* __restrict__ esq,
    float* __restrict__ out_q,
    float* __restrict__ out_idx) {
    const int n  = blockIdx.x * 256 + threadIdx.x;
    const int b  = n >> 12;        // n / 4096
    const int hw = n & 4095;       // h*64 + w  (lanes consecutive in w -> coalesced)

    // Row x[b, :, h, w]: 64 named-scalar loads, coalesced across lanes.
    const float* xp = x + b * (VQ_D * VQ_HW) + hw;
    float4 X0, X1, X2, X3, X4, X5, X6, X7, X8, X9, X10, X11, X12, X13, X14, X15;
    LD4(X0, 0)   LD4(X1, 4)   LD4(X2, 8)   LD4(X3, 12)
    LD4(X4, 16)  LD4(X5, 20)  LD4(X6, 24)  LD4(X7, 28)
    LD4(X8, 32)  LD4(X9, 36)  LD4(X10, 40) LD4(X11, 44)
    LD4(X12, 48) LD4(X13, 52) LD4(X14, 56) LD4(X15, 60)

    float best = 3.4e38f;
    int bidx = 0;

    for (int k0 = 0; k0 < VQ_K; k0 += 8) {
        float acc0 = 0.f, acc1 = 0.f, acc2 = 0.f, acc3 = 0.f;
        float acc4 = 0.f, acc5 = 0.f, acc6 = 0.f, acc7 = 0.f;
        const float* e0 = embed + k0 * VQ_D;   // wave-uniform -> scalar loads
        BLK4(X0, 0)   BLK4(X1, 4)   BLK4(X2, 8)   BLK4(X3, 12)
        BLK4(X4, 16)  BLK4(X5, 20)  BLK4(X6, 24)  BLK4(X7, 28)
        BLK4(X8, 32)  BLK4(X9, 36)  BLK4(X10, 40) BLK4(X11, 44)
        BLK4(X12, 48) BLK4(X13, 52) BLK4(X14, 56) BLK4(X15, 60)

        float dist;
        // ascending k + strict < == numpy first-min argmin; FMA order per chain
        // identical to the R1-passing kernel -> bitwise-same distances.
        dist = fmaf(-2.f, acc0, esq[k0 + 0]); if (dist < best) { best = dist; bidx = k0 + 0; }
        dist = fmaf(-2.f, acc1, esq[k0 + 1]); if (dist < best) { best = dist; bidx = k0 + 1; }
        dist = fmaf(-2.f, acc2, esq[k0 + 2]); if (dist < best) { best = dist; bidx = k0 + 2; }
        dist = fmaf(-2.f, acc3, esq[k0 + 3]); if (dist < best) { best = dist; bidx = k0 + 3; }
        dist = fmaf(-2.f, acc4, esq[k0 + 4]); if (dist < best) { best = dist; bidx = k0 + 4; }
        dist = fmaf(-2.f, acc5, esq[k0 + 5]); if (dist < best) { best = dist; bidx = k0 + 5; }
        dist = fmaf(-2.f, acc6, esq[k0 + 6]); if (dist < best) { best = dist; bidx = k0 + 6; }
        dist = fmaf(-2.f, acc7, esq[k0 + 7]); if (dist < best) { best = dist; bidx = k0 + 7; }
    }

    // indices (exact float values 0..511)
    out_idx[n] = (float)bidx;

    // quantized row = embed[bidx], 16 x float4 gather/store (L2-resident gather)
    const float4* e4 = (const float4*)(embed + bidx * VQ_D);
    float4* o4 = (float4*)(out_q + (size_t)n * VQ_D);
#pragma unroll
    for (int c = 0; c < VQ_D / 4; ++c) o4[c] = e4[c];
}

extern "C" void kernel_launch(void* const* d_in, const int* in_sizes, int n_in,
                              void* d_out, int out_size, void* d_ws, size_t ws_size,
                              hipStream_t stream) {
    const float* x     = (const float*)d_in[0];
    const float* embed = (const float*)d_in[1];
    float* out_q   = (float*)d_out;                        // N*64 quantized
    float* out_idx = (float*)d_out + (size_t)VQ_N * VQ_D;  // N indices
    float* esq     = (float*)d_ws;                         // K floats scratch

    vq_esq_kernel<<<2, 256, 0, stream>>>(embed, esq);
    vq_main_kernel<<<VQ_N / 256, 256, 0, stream>>>(x, embed, esq, out_q, out_idx);
}

// Round 3
// 412.641 us; speedup vs baseline: 1.0246x; 1.0246x over previous
//
#include <hip/hip_runtime.h>

// VQ: x (32,64,64,64) fp32 NCHW, embed (512,64) fp32.
// N = 131072 rows of D=64; K=512 codes.
// out = [quantized: N*64 floats (NHWC)] ++ [indices: N floats]
//
// R3: __launch_bounds__(256, 4). R1/R2 had VGPR_Count=36 — the backend's
// default occupancy heuristic capped registers and spilled the 64-float X row
// to scratch (WRITE_SIZE 146MB = dirty scratch evictions thrashing L2;
// VALUBusy 34% = waiting on scratch reloads). min 4 waves/EU -> 128-VGPR
// budget; X row fits. asm pin prevents load sinking/remat into the k-loop.

#define VQ_N 131072
#define VQ_D 64
#define VQ_K 512
#define VQ_HW 4096   // H*W = 64*64

__global__ __launch_bounds__(256) void vq_esq_kernel(
    const float* __restrict__ embed, float* __restrict__ esq) {
    int k = blockIdx.x * blockDim.x + threadIdx.x;
    if (k >= VQ_K) return;
    const float* e = embed + k * VQ_D;
    float p0 = 0.f, p1 = 0.f, p2 = 0.f, p3 = 0.f;
#pragma unroll
    for (int d = 0; d < VQ_D; d += 4) {
        p0 = fmaf(e[d + 0], e[d + 0], p0);
        p1 = fmaf(e[d + 1], e[d + 1], p1);
        p2 = fmaf(e[d + 2], e[d + 2], p2);
        p3 = fmaf(e[d + 3], e[d + 3], p3);
    }
    esq[k] = (p0 + p1) + (p2 + p3);
}

// one FMA into each of the 8 chains for x-scalar xv at depth d
#define ROW8(xv, d)                                  \
    acc0 = fmaf(xv, e0[0 * VQ_D + (d)], acc0);       \
    acc1 = fmaf(xv, e0[1 * VQ_D + (d)], acc1);       \
    acc2 = fmaf(xv, e0[2 * VQ_D + (d)], acc2);       \
    acc3 = fmaf(xv, e0[3 * VQ_D + (d)], acc3);       \
    acc4 = fmaf(xv, e0[4 * VQ_D + (d)], acc4);       \
    acc5 = fmaf(xv, e0[5 * VQ_D + (d)], acc5);       \
    acc6 = fmaf(xv, e0[6 * VQ_D + (d)], acc6);       \
    acc7 = fmaf(xv, e0[7 * VQ_D + (d)], acc7);

#define BLK4(Xv, dbase)                              \
    ROW8((Xv).x, (dbase) + 0)                        \
    ROW8((Xv).y, (dbase) + 1)                        \
    ROW8((Xv).z, (dbase) + 2)                        \
    ROW8((Xv).w, (dbase) + 3)

#define LD4(Xv, c)                                   \
    (Xv).x = xp[((c) + 0) * VQ_HW];                  \
    (Xv).y = xp[((c) + 1) * VQ_HW];                  \
    (Xv).z = xp[((c) + 2) * VQ_HW];                  \
    (Xv).w = xp[((c) + 3) * VQ_HW];

// opaque to the optimizer: forces the 4 components into live VGPRs here and
// blocks sinking/remat of the producing loads into the k-loop
#define PIN4(Xv)                                     \
    asm volatile("" : "+v"((Xv).x), "+v"((Xv).y), "+v"((Xv).z), "+v"((Xv).w));

__global__ __launch_bounds__(256, 4) void vq_main_kernel(
    const float* __restrict__ x,
    const float* __restrict__ embed,
    const float* __restrict__ esq,
    float* __restrict__ out_q,
    float* __restrict__ out_idx) {
    const int n  = blockIdx.x * 256 + threadIdx.x;
    const int b  = n >> 12;        // n / 4096
    const int hw = n & 4095;       // h*64 + w  (lanes consecutive in w -> coalesced)

    // Row x[b, :, h, w]: 64 scalar loads, coalesced across lanes.
    const float* xp = x + b * (VQ_D * VQ_HW) + hw;
    float4 X0, X1, X2, X3, X4, X5, X6, X7, X8, X9, X10, X11, X12, X13, X14, X15;
    LD4(X0, 0)   LD4(X1, 4)   LD4(X2, 8)   LD4(X3, 12)
    LD4(X4, 16)  LD4(X5, 20)  LD4(X6, 24)  LD4(X7, 28)
    LD4(X8, 32)  LD4(X9, 36)  LD4(X10, 40) LD4(X11, 44)
    LD4(X12, 48) LD4(X13, 52) LD4(X14, 56) LD4(X15, 60)
    PIN4(X0)  PIN4(X1)  PIN4(X2)  PIN4(X3)
    PIN4(X4)  PIN4(X5)  PIN4(X6)  PIN4(X7)
    PIN4(X8)  PIN4(X9)  PIN4(X10) PIN4(X11)
    PIN4(X12) PIN4(X13) PIN4(X14) PIN4(X15)

    float best = 3.4e38f;
    int bidx = 0;

    for (int k0 = 0; k0 < VQ_K; k0 += 8) {
        float acc0 = 0.f, acc1 = 0.f, acc2 = 0.f, acc3 = 0.f;
        float acc4 = 0.f, acc5 = 0.f, acc6 = 0.f, acc7 = 0.f;
        const float* e0 = embed + k0 * VQ_D;   // wave-uniform -> scalar loads
        BLK4(X0, 0)   BLK4(X1, 4)   BLK4(X2, 8)   BLK4(X3, 12)
        BLK4(X4, 16)  BLK4(X5, 20)  BLK4(X6, 24)  BLK4(X7, 28)
        BLK4(X8, 32)  BLK4(X9, 36)  BLK4(X10, 40) BLK4(X11, 44)
        BLK4(X12, 48) BLK4(X13, 52) BLK4(X14, 56) BLK4(X15, 60)

        float dist;
        // ascending k + strict < == numpy first-min argmin; FMA order per chain
        // identical to the R1-passing kernel -> bitwise-same distances.
        dist = fmaf(-2.f, acc0, esq[k0 + 0]); if (dist < best) { best = dist; bidx = k0 + 0; }
        dist = fmaf(-2.f, acc1, esq[k0 + 1]); if (dist < best) { best = dist; bidx = k0 + 1; }
        dist = fmaf(-2.f, acc2, esq[k0 + 2]); if (dist < best) { best = dist; bidx = k0 + 2; }
        dist = fmaf(-2.f, acc3, esq[k0 + 3]); if (dist < best) { best = dist; bidx = k0 + 3; }
        dist = fmaf(-2.f, acc4, esq[k0 + 4]); if (dist < best) { best = dist; bidx = k0 + 4; }
        dist = fmaf(-2.f, acc5, esq[k0 + 5]); if (dist < best) { best = dist; bidx = k0 + 5; }
        dist = fmaf(-2.f, acc6, esq[k0 + 6]); if (dist < best) { best = dist; bidx = k0 + 6; }
        dist = fmaf(-2.f, acc7, esq[k0 + 7]); if (dist < best) { best = dist; bidx = k0 + 7; }
    }

    // indices (exact float values 0..511)
    out_idx[n] = (float)bidx;

    // quantized row = embed[bidx], 16 x float4 gather/store (L2-resident gather)
    const float4* e4 = (const float4*)(embed + bidx * VQ_D);
    float4* o4 = (float4*)(out_q + (size_t)n * VQ_D);
#pragma unroll
    for (int c = 0; c < VQ_D / 4; ++c) o4[c] = e4[c];
}

extern "C" void kernel_launch(void* const* d_in, const int* in_sizes, int n_in,
                              void* d_out, int out_size, void* d_ws, size_t ws_size,
                              hipStream_t stream) {
    const float* x     = (const float*)d_in[0];
    const float* embed = (const float*)d_in[1];
    float* out_q   = (float*)d_out;                        // N*64 quantized
    float* out_idx = (float*)d_out + (size_t)VQ_N * VQ_D;  // N indices
    float* esq     = (float*)d_ws;                         // K floats scratch

    vq_esq_kernel<<<2, 256, 0, stream>>>(embed, esq);
    vq_main_kernel<<<VQ_N / 256, 256, 0, stream>>>(x, embed, esq, out_q, out_idx);
}

// Round 4
// 292.481 us; speedup vs baseline: 1.4456x; 1.4108x over previous
//
#include <hip/hip_runtime.h>

// VQ: x (32,64,64,64) fp32 NCHW, embed (512,64) fp32.
// N = 131072 rows of D=64; K=512 codes.
// out = [quantized: N*64 floats (NHWC)] ++ [indices: N floats]
//
// R4: X row staged in LDS, not VGPRs. R1-R3 all compiled to VGPR_Count=36 with
// the 64-float row spilled to scratch (WRITE_SIZE 146MB churn, VALUBusy 34%);
// launch_bounds and asm pins changed nothing. LDS tiling removes the long-lived
// register demand, and the 65KB LDS caps occupancy at 2 blocks/CU so the
// backend's occupancy heuristic itself relaxes the register budget.
// An opaque zero offset (koff) blocks LICM from hoisting the 64 ds_reads out
// of the k-loop (which would recreate the 64-live-VGPR spill).

#define VQ_N 131072
#define VQ_D 64
#define VQ_K 512
#define VQ_HW 4096    // H*W
#define XS_STRIDE 65  // +1 pad: LDS bank (t+d)%32 -> 2 lanes/bank = conflict-free

__global__ __launch_bounds__(256) void vq_esq_kernel(
    const float* __restrict__ embed, float* __restrict__ esq) {
    int k = blockIdx.x * blockDim.x + threadIdx.x;
    if (k >= VQ_K) return;
    const float* e = embed + k * VQ_D;
    float p0 = 0.f, p1 = 0.f, p2 = 0.f, p3 = 0.f;
#pragma unroll
    for (int d = 0; d < VQ_D; d += 4) {
        p0 = fmaf(e[d + 0], e[d + 0], p0);
        p1 = fmaf(e[d + 1], e[d + 1], p1);
        p2 = fmaf(e[d + 2], e[d + 2], p2);
        p3 = fmaf(e[d + 3], e[d + 3], p3);
    }
    esq[k] = (p0 + p1) + (p2 + p3);
}

__global__ __launch_bounds__(256, 2) void vq_main_kernel(
    const float* __restrict__ x,
    const float* __restrict__ embed,
    const float* __restrict__ esq,
    float* __restrict__ out_q,
    float* __restrict__ out_idx) {
    __shared__ float Xs[256 * XS_STRIDE];   // 66560 B -> 2 blocks/CU

    const int t   = threadIdx.x;
    const int n0  = blockIdx.x * 256;       // block's first row
    const int n   = n0 + t;
    const int b   = n0 >> 12;               // 4096 rows per image; 256 | 4096
    const int hw0 = n0 & 4095;

    // Stage 256 rows: for each channel d, lanes load consecutive hw (coalesced),
    // write Xs[t][d] with stride-65 padding (bank (t+d)%32, 2-way = free).
    const float* xb = x + (size_t)b * (VQ_D * VQ_HW) + hw0;
#pragma unroll
    for (int d = 0; d < VQ_D; ++d)
        Xs[t * XS_STRIDE + d] = xb[d * VQ_HW + t];
    __syncthreads();

    float best = 3.4e38f;
    int bidx = 0;

    for (int k0 = 0; k0 < VQ_K; k0 += 8) {
        // Opaque runtime-zero offset: k0<512 so (koff>>16)==0, but the asm
        // makes it unprovable -> Xs reads can't be hoisted/CSE'd across k0.
        unsigned koff = (unsigned)k0;
        asm("" : "+v"(koff));
        const float* xr = &Xs[t * XS_STRIDE + (koff >> 16)];

        float acc0 = 0.f, acc1 = 0.f, acc2 = 0.f, acc3 = 0.f;
        float acc4 = 0.f, acc5 = 0.f, acc6 = 0.f, acc7 = 0.f;
        const float* e0 = embed + k0 * VQ_D;   // wave-uniform -> scalar loads
#pragma unroll
        for (int d = 0; d < VQ_D; ++d) {
            const float xv = xr[d];            // ds_read_b32, short-lived reg
            acc0 = fmaf(xv, e0[0 * VQ_D + d], acc0);
            acc1 = fmaf(xv, e0[1 * VQ_D + d], acc1);
            acc2 = fmaf(xv, e0[2 * VQ_D + d], acc2);
            acc3 = fmaf(xv, e0[3 * VQ_D + d], acc3);
            acc4 = fmaf(xv, e0[4 * VQ_D + d], acc4);
            acc5 = fmaf(xv, e0[5 * VQ_D + d], acc5);
            acc6 = fmaf(xv, e0[6 * VQ_D + d], acc6);
            acc7 = fmaf(xv, e0[7 * VQ_D + d], acc7);
        }

        float dist;
        // ascending k + strict < == numpy first-min argmin; per-chain FMA order
        // identical to the R1-passing kernel -> bitwise-same distances.
        dist = fmaf(-2.f, acc0, esq[k0 + 0]); if (dist < best) { best = dist; bidx = k0 + 0; }
        dist = fmaf(-2.f, acc1, esq[k0 + 1]); if (dist < best) { best = dist; bidx = k0 + 1; }
        dist = fmaf(-2.f, acc2, esq[k0 + 2]); if (dist < best) { best = dist; bidx = k0 + 2; }
        dist = fmaf(-2.f, acc3, esq[k0 + 3]); if (dist < best) { best = dist; bidx = k0 + 3; }
        dist = fmaf(-2.f, acc4, esq[k0 + 4]); if (dist < best) { best = dist; bidx = k0 + 4; }
        dist = fmaf(-2.f, acc5, esq[k0 + 5]); if (dist < best) { best = dist; bidx = k0 + 5; }
        dist = fmaf(-2.f, acc6, esq[k0 + 6]); if (dist < best) { best = dist; bidx = k0 + 6; }
        dist = fmaf(-2.f, acc7, esq[k0 + 7]); if (dist < best) { best = dist; bidx = k0 + 7; }
    }

    // indices (exact float values 0..511)
    out_idx[n] = (float)bidx;

    // quantized row = embed[bidx], 16 x float4 gather/store (embed L2-resident)
    const float4* e4 = (const float4*)(embed + bidx * VQ_D);
    float4* o4 = (float4*)(out_q + (size_t)n * VQ_D);
#pragma unroll
    for (int c = 0; c < VQ_D / 4; ++c) o4[c] = e4[c];
}

extern "C" void kernel_launch(void* const* d_in, const int* in_sizes, int n_in,
                              void* d_out, int out_size, void* d_ws, size_t ws_size,
                              hipStream_t stream) {
    const float* x     = (const float*)d_in[0];
    const float* embed = (const float*)d_in[1];
    float* out_q   = (float*)d_out;                        // N*64 quantized
    float* out_idx = (float*)d_out + (size_t)VQ_N * VQ_D;  // N indices
    float* esq     = (float*)d_ws;                         // K floats scratch

    vq_esq_kernel<<<2, 256, 0, stream>>>(embed, esq);
    vq_main_kernel<<<VQ_N / 256, 256, 0, stream>>>(x, embed, esq, out_q, out_idx);
}

// Round 6
// 154.102 us; speedup vs baseline: 2.7437x; 1.8980x over previous
//
#include <hip/hip_runtime.h>

// VQ via MFMA: x (32,64,64,64) fp32 NCHW, embed (512,64) fp32.
// bf16 hi/lo split (3 MFMA passes, fp32 acc) used for PRUNING only; every
// candidate within EPS of the row-min is re-checked in exact fp32 (same fmaf
// order as the R1-passing scalar kernel) -> argmin matches np bit-exactly.
//
// R6 fix: R5's "+2048" float-ordering bias rounded distances to ulp 2^-12
// before the atomicMin key compare -> false ties -> ~5 rows picked the
// smaller-index near-tie instead of np's true min (indices absmax 322,
// quantized still passed). Replaced with the lossless order-preserving
// float->uint bit transform. EPS widened 0.0625 -> 0.25 (6x error margin).

#define VQ_N 131072
#define VQ_D 64
#define VQ_K 512
#define VQ_HW 4096
#define ROWS 64          // rows per block
#define EPS 0.25f        // prune margin; approx-vs-exact |delta| <~ 0.04
#define QMAX 1024
#define XH_STR 72        // shorts/row (64+8 pad), 144B row stride (16B-aligned)
#define X32_STR 68       // floats/row, 16B-aligned

typedef __attribute__((ext_vector_type(8))) short short8;
typedef __attribute__((ext_vector_type(4))) float f32x4;

static __device__ __forceinline__ unsigned short f2bf(float f) {
    unsigned u = __float_as_uint(f);
    unsigned r = (u + 0x7fffu + ((u >> 16) & 1u)) >> 16;   // round-nearest-even
    return (unsigned short)r;
}
static __device__ __forceinline__ float bf2f(unsigned short h) {
    return __uint_as_float(((unsigned)h) << 16);
}
// order-preserving float -> uint (monotone, lossless; handles negatives)
static __device__ __forceinline__ unsigned fenc(float f) {
    unsigned u = __float_as_uint(f);
    return (u >> 31) ? ~u : (u | 0x80000000u);
}
static __device__ __forceinline__ float fdec(unsigned k) {
    return (k & 0x80000000u) ? __uint_as_float(k ^ 0x80000000u)
                             : __uint_as_float(~k);
}

__global__ __launch_bounds__(256) void vq_esq_kernel(
    const float* __restrict__ embed, float* __restrict__ esq) {
    int k = blockIdx.x * blockDim.x + threadIdx.x;
    if (k >= VQ_K) return;
    const float* e = embed + k * VQ_D;
    float p0 = 0.f, p1 = 0.f, p2 = 0.f, p3 = 0.f;
#pragma unroll
    for (int d = 0; d < VQ_D; d += 4) {
        p0 = fmaf(e[d + 0], e[d + 0], p0);
        p1 = fmaf(e[d + 1], e[d + 1], p1);
        p2 = fmaf(e[d + 2], e[d + 2], p2);
        p3 = fmaf(e[d + 3], e[d + 3], p3);
    }
    esq[k] = (p0 + p1) + (p2 + p3);
}

// embed fp32 -> bf16 hi/lo arrays (EH, EL), 512*64 each
__global__ __launch_bounds__(256) void vq_prep_kernel(
    const float* __restrict__ embed,
    unsigned short* __restrict__ EH, unsigned short* __restrict__ EL) {
    int g = blockIdx.x * 256 + threadIdx.x;   // 32768 elems
    float f = embed[g];
    unsigned short h = f2bf(f);
    EH[g] = h;
    EL[g] = f2bf(f - bf2f(h));
}

__global__ __launch_bounds__(256, 2) void vq_mfma_kernel(
    const float* __restrict__ x, const float* __restrict__ embed,
    const float* __restrict__ esq,
    const unsigned short* __restrict__ EH, const unsigned short* __restrict__ EL,
    float* __restrict__ out_q, float* __restrict__ out_idx) {
    __shared__ __align__(16) unsigned short XsH[ROWS * XH_STR];
    __shared__ __align__(16) unsigned short XsL[ROWS * XH_STR];
    __shared__ __align__(16) float Xs32[ROWS * X32_STR];
    __shared__ unsigned row_minb[ROWS];            // fenc(approx row min)
    __shared__ unsigned long long row_best[ROWS];  // (fenc(exact dist)<<32)|n
    __shared__ int qcount;
    __shared__ unsigned qbuf[QMAX];

    const int t   = threadIdx.x;
    const int n0  = blockIdx.x * ROWS;
    const int b   = n0 >> 12;        // 64 | 4096 -> block stays in one image
    const int hw0 = n0 & 4095;

    if (t < ROWS) { row_minb[t] = 0xFFFFFFFFu; row_best[t] = ~0ull; }
    if (t == 0) qcount = 0;

    // ---- stage X: 64 rows x 64 ch; global loads coalesced over hw ----
    {
        const int hw = t & 63;
        const int d0 = (t >> 6) * 16;
        const float* xb = x + (size_t)b * (VQ_D * VQ_HW) + hw0 + hw;
#pragma unroll
        for (int dd = 0; dd < 16; ++dd) {
            int d = d0 + dd;
            float f = xb[d * VQ_HW];
            unsigned short h = f2bf(f);
            XsH[hw * XH_STR + d] = h;
            XsL[hw * XH_STR + d] = f2bf(f - bf2f(h));
            Xs32[hw * X32_STR + d] = f;
        }
    }
    __syncthreads();

    const int lane = t & 63;
    const int wave = t >> 6;
    const int lrow = lane & 15;
    const int quad = lane >> 4;
    const int nb   = wave * 128;     // this wave's codebook range: 128 codes

    // ---- A fragments (cached in regs): A[m=lane&15][k=quad*8+j] ----
    short8 AH[4][2], AL[4][2];
#pragma unroll
    for (int rt = 0; rt < 4; ++rt)
#pragma unroll
        for (int kk = 0; kk < 2; ++kk) {
            int off = (rt * 16 + lrow) * XH_STR + kk * 32 + quad * 8;
            AH[rt][kk] = *(const short8*)&XsH[off];
            AL[rt][kk] = *(const short8*)&XsL[off];
        }

    float esqv[8];
#pragma unroll
    for (int nt = 0; nt < 8; ++nt) esqv[nt] = esq[nb + nt * 16 + lrow];

    float v1[4][4], v2[4][4];
    int   n1[4][4], n2[4][4];
#pragma unroll
    for (int rt = 0; rt < 4; ++rt)
#pragma unroll
        for (int i = 0; i < 4; ++i) {
            v1[rt][i] = 1e30f; v2[rt][i] = 1e30f; n1[rt][i] = 0; n2[rt][i] = 0;
        }

    // ---- pass 1: approx dists via MFMA, track per-lane min1/min2 ----
#pragma unroll
    for (int nt = 0; nt < 8; ++nt) {
        const int n16  = nb + nt * 16;
        const int eoff = (n16 + lrow) * VQ_D;   // B[k][n]: n=lane&15, k=quad*8+j
        short8 BH0 = *(const short8*)&EH[eoff + quad * 8];
        short8 BH1 = *(const short8*)&EH[eoff + 32 + quad * 8];
        short8 BL0 = *(const short8*)&EL[eoff + quad * 8];
        short8 BL1 = *(const short8*)&EL[eoff + 32 + quad * 8];
        const int nn = n16 + lrow;
#pragma unroll
        for (int rt = 0; rt < 4; ++rt) {
            f32x4 acc = {0.f, 0.f, 0.f, 0.f};
            acc = __builtin_amdgcn_mfma_f32_16x16x32_bf16(AH[rt][0], BH0, acc, 0, 0, 0);
            acc = __builtin_amdgcn_mfma_f32_16x16x32_bf16(AH[rt][1], BH1, acc, 0, 0, 0);
            acc = __builtin_amdgcn_mfma_f32_16x16x32_bf16(AH[rt][0], BL0, acc, 0, 0, 0);
            acc = __builtin_amdgcn_mfma_f32_16x16x32_bf16(AH[rt][1], BL1, acc, 0, 0, 0);
            acc = __builtin_amdgcn_mfma_f32_16x16x32_bf16(AL[rt][0], BH0, acc, 0, 0, 0);
            acc = __builtin_amdgcn_mfma_f32_16x16x32_bf16(AL[rt][1], BH1, acc, 0, 0, 0);
#pragma unroll
            for (int i = 0; i < 4; ++i) {     // C: col=lane&15, row=quad*4+i
                float v = fmaf(-2.f, acc[i], esqv[nt]);
                if (v < v1[rt][i])      { v2[rt][i] = v1[rt][i]; n2[rt][i] = n1[rt][i];
                                          v1[rt][i] = v;         n1[rt][i] = nn; }
                else if (v < v2[rt][i]) { v2[rt][i] = v;         n2[rt][i] = nn; }
            }
        }
    }

    // ---- row-min across the 16 n-lanes, then across waves via LDS ----
#pragma unroll
    for (int rt = 0; rt < 4; ++rt)
#pragma unroll
        for (int i = 0; i < 4; ++i) {
            float r = v1[rt][i];
            r = fminf(r, __shfl_xor(r, 1));
            r = fminf(r, __shfl_xor(r, 2));
            r = fminf(r, __shfl_xor(r, 4));
            r = fminf(r, __shfl_xor(r, 8));
            if (lrow == 0) {
                int m = rt * 16 + quad * 4 + i;
                atomicMin(&row_minb[m], fenc(r));   // lossless ordering
            }
        }
    __syncthreads();

    // ---- push candidates (within EPS of row-min) to queue ----
#pragma unroll
    for (int rt = 0; rt < 4; ++rt)
#pragma unroll
        for (int i = 0; i < 4; ++i) {
            int m = rt * 16 + quad * 4 + i;
            float thr = fdec(row_minb[m]) + EPS;
            if (v1[rt][i] <= thr) {
                int id = atomicAdd(&qcount, 1);
                if (id < QMAX) qbuf[id] = ((unsigned)m << 16) | (unsigned)n1[rt][i];
            }
            if (v2[rt][i] <= thr) {
                int id = atomicAdd(&qcount, 1);
                if (id < QMAX) qbuf[id] = ((unsigned)m << 16) | (unsigned)n2[rt][i];
            }
        }
    __syncthreads();

    // ---- exact fp32 recheck of candidates (same fmaf order as R1 kernel) ----
    int qc = qcount; if (qc > QMAX) qc = QMAX;
    for (int qi = t; qi < qc; qi += 256) {
        unsigned e = qbuf[qi];
        int m = (int)(e >> 16), n = (int)(e & 0xffffu);
        const float4* er = (const float4*)(embed + n * VQ_D);
        const float4* xr = (const float4*)&Xs32[m * X32_STR];
        float dot = 0.f;
#pragma unroll
        for (int d4 = 0; d4 < 16; ++d4) {
            float4 ev = er[d4]; float4 xv = xr[d4];
            dot = fmaf(xv.x, ev.x, dot);
            dot = fmaf(xv.y, ev.y, dot);
            dot = fmaf(xv.z, ev.z, dot);
            dot = fmaf(xv.w, ev.w, dot);
        }
        float v = fmaf(-2.f, dot, esq[n]);
        unsigned long long key =
            (((unsigned long long)fenc(v)) << 32) | (unsigned)n;
        atomicMin(&row_best[m], key);   // exact order; equal dist -> smaller n
    }
    __syncthreads();

    // ---- outputs: indices + fully-coalesced quantized rows ----
    if (t < ROWS) out_idx[n0 + t] = (float)(unsigned)(row_best[t] & 0xffffffffu);

#pragma unroll
    for (int it = 0; it < 4; ++it) {
        int f   = it * 1024 + t * 4;          // lane-contiguous within block
        int row = f >> 6;
        int col = f & 63;
        unsigned k = (unsigned)(row_best[row] & 0xffffffffu);
        float4 val = *(const float4*)(embed + k * VQ_D + col);
        *(float4*)(out_q + (size_t)n0 * VQ_D + f) = val;
    }
}

extern "C" void kernel_launch(void* const* d_in, const int* in_sizes, int n_in,
                              void* d_out, int out_size, void* d_ws, size_t ws_size,
                              hipStream_t stream) {
    const float* x     = (const float*)d_in[0];
    const float* embed = (const float*)d_in[1];
    float* out_q   = (float*)d_out;
    float* out_idx = (float*)d_out + (size_t)VQ_N * VQ_D;

    float* esq          = (float*)d_ws;                          // 512 f
    unsigned short* EH  = (unsigned short*)((char*)d_ws + 2048);
    unsigned short* EL  = (unsigned short*)((char*)d_ws + 2048 + VQ_K * VQ_D * 2);

    vq_esq_kernel<<<2, 256, 0, stream>>>(embed, esq);
    vq_prep_kernel<<<(VQ_K * VQ_D) / 256, 256, 0, stream>>>(embed, EH, EL);
    vq_mfma_kernel<<<VQ_N / ROWS, 256, 0, stream>>>(x, embed, esq, EH, EL, out_q, out_idx);
}